// Round 3
// baseline (1217.286 us; speedup 1.0000x reference)
//
#include <hip/hip_runtime.h>
#include <stdint.h>

using f32x4  = __attribute__((ext_vector_type(4))) float;
using bf16x8 = __attribute__((ext_vector_type(8))) __bf16;

// ---------------------------------------------------------------------------
// x (fp32) -> bf16 activations
// ---------------------------------------------------------------------------
__global__ void cvt_x_kernel(const float* __restrict__ x, __bf16* __restrict__ out) {
    const int t = blockIdx.x * blockDim.x + threadIdx.x;
    const size_t base = (size_t)t * 8;
    const float4 a = *(const float4*)(x + base);
    const float4 b = *(const float4*)(x + base + 4);
    bf16x8 pv;
    pv[0] = (__bf16)a.x; pv[1] = (__bf16)a.y; pv[2] = (__bf16)a.z; pv[3] = (__bf16)a.w;
    pv[4] = (__bf16)b.x; pv[5] = (__bf16)b.y; pv[6] = (__bf16)b.z; pv[7] = (__bf16)b.w;
    *(bf16x8*)(out + base) = pv;
}

// ---------------------------------------------------------------------------
// E (N x 9, fp32) -> Et (9 x N, fp32)
// ---------------------------------------------------------------------------
__global__ void prep_et_kernel(const float* __restrict__ E, float* __restrict__ Et) {
    const int n = blockIdx.x * 256 + threadIdx.x;
#pragma unroll
    for (int q = 0; q < 9; ++q) Et[(size_t)q * 65536 + n] = E[(size_t)n * 9 + q];
}

// ---------------------------------------------------------------------------
// Build Bt[o][k] bf16 panel: k = r*I + i -> W[r][o][i]; rows RI..RI+8 = bias;
// rows RI+9..KEXT-1 = 0.   KEXT = RI + 64.
// ---------------------------------------------------------------------------
template<int I, int O>
__global__ void prep_w_kernel(const float* __restrict__ W, const float* __restrict__ b,
                              __bf16* __restrict__ Bt) {
    constexpr int RI = 9 * I;
    constexpr int KEXT = RI + 64;
    const int o  = blockIdx.y;
    const int kc = blockIdx.x * blockDim.x + threadIdx.x;
    if (kc >= (KEXT >> 3)) return;
    const int k0 = kc << 3;
    bf16x8 pv;
#pragma unroll
    for (int q = 0; q < 8; ++q) {
        const int k = k0 + q;
        float v;
        if (k < RI) {
            const int r = k / I;
            const int i = k & (I - 1);
            v = W[((size_t)r * O + o) * I + i];
        } else if (k - RI < 9) {
            v = b[(size_t)(k - RI) * O + o];
        } else {
            v = 0.f;
        }
        pv[q] = (__bf16)v;
    }
    *(bf16x8*)(Bt + (size_t)o * KEXT + k0) = pv;
}

// ---------------------------------------------------------------------------
// Relation-mixed GEMM, A-fragments hoisted to registers across the 9-r fold:
//   y[n,o] = sum_r e[n,r] * ( sum_i x[n,i] W[r,o,i] ) + sum_r e[n,r] b[r,o]
// Per 128-col i-chunk: stage A once -> load A-frags into regs (reused 9x);
// B double-buffered across r (ldsA reused as B's partner buffer), 2-phase
// rhythm: issue next-B stage, compute current, one vmcnt-drain barrier/iter.
// Fold acc += e_r * t with e from Et (global, L1-resident broadcast).
// 128x128 tile, 4 waves, mfma_f32_16x16x32_bf16, T2 chunk-XOR swizzle.
// ---------------------------------------------------------------------------
template<int I, int O, bool RELU, bool OUTF32>
__global__ __launch_bounds__(256, 2)
void kg_gemm(const __bf16* __restrict__ A, const float* __restrict__ E,
             const float* __restrict__ Et, const __bf16* __restrict__ Bt,
             void* __restrict__ Outv) {
    constexpr int RI   = 9 * I;
    constexpr int KEXT = RI + 64;
    constexpr int NCH  = I >> 7;
    constexpr int NBN  = O >> 7;
    static_assert((I & 127) == 0 && (O & 127) == 0, "tile divisibility");

    __shared__ __align__(16) char lds[65536];
    char* const ldsA = lds;
    char* const ldsB = lds + 32768;

    const int tid  = threadIdx.x;
    const int nwg  = gridDim.x;
    const int braw = blockIdx.x;
    const int bid  = (braw & 7) * (nwg >> 3) + (braw >> 3);   // XCD swizzle
    const int bm0  = (bid / NBN) << 7;
    const int bn0  = (bid % NBN) << 7;
    const int lane = tid & 63;
    const int wid  = tid >> 6;
    const int wr   = (wid >> 1) << 6;
    const int wc   = (wid & 1) << 6;
    const int l15  = lane & 15;
    const int lq   = lane >> 4;

    f32x4 acc[4][4];
#pragma unroll
    for (int m = 0; m < 4; ++m)
#pragma unroll
        for (int n = 0; n < 4; ++n)
            acc[m][n] = f32x4{0.f, 0.f, 0.f, 0.f};

    // stage a 128x128 bf16 tile: linear LDS dest, XOR-pre-swizzled global src
    auto stage128 = [&](char* dst, const __bf16* base, int rowStride) {
#pragma unroll
        for (int rr = 0; rr < 8; ++rr) {
            const int q    = rr * 256 + tid;
            const int row  = q >> 4;
            const int jsrc = (q & 15) ^ (row & 7);
            __builtin_amdgcn_global_load_lds(
                (const __attribute__((address_space(1))) void*)
                    (base + (size_t)row * rowStride + (jsrc << 3)),
                (__attribute__((address_space(3))) void*)(dst + q * 16), 16, 0, 0);
        }
    };

    bf16x8 af[4][4];   // A fragments, live across all 9 relations of a chunk

    auto computeR = [&](const char* buf, int r) {
        f32x4 ev[4];
#pragma unroll
        for (int m = 0; m < 4; ++m)
            ev[m] = *(const f32x4*)(Et + (size_t)r * 65536 + bm0 + wr + m * 16 + lq * 4);
#pragma unroll
        for (int n = 0; n < 4; ++n) {
            const int rb = wc + n * 16 + l15;
            bf16x8 bvk[4];
#pragma unroll
            for (int ks = 0; ks < 4; ++ks)
                bvk[ks] = *(const bf16x8*)(buf + rb * 256 + ((((ks << 2) + lq) ^ (rb & 7)) << 4));
#pragma unroll
            for (int m = 0; m < 4; ++m) {
                f32x4 t = {0.f, 0.f, 0.f, 0.f};
#pragma unroll
                for (int ks = 0; ks < 4; ++ks)
                    t = __builtin_amdgcn_mfma_f32_16x16x32_bf16(af[m][ks], bvk[ks], t, 0, 0, 0);
                acc[m][n] += ev[m] * t;
            }
        }
    };

#pragma unroll 1
    for (int c = 0; c < NCH; ++c) {
        const __bf16* Bc = Bt + (size_t)bn0 * KEXT + (c << 7);
        stage128(ldsA, A + (size_t)bm0 * I + (c << 7), I);
        stage128(ldsB, Bc, KEXT);
        __syncthreads();                       // A + B[0] resident
#pragma unroll
        for (int m = 0; m < 4; ++m) {
            const int ra = wr + m * 16 + l15;
#pragma unroll
            for (int ks = 0; ks < 4; ++ks)
                af[m][ks] = *(const bf16x8*)(ldsA + ra * 256 + ((((ks << 2) + lq) ^ (ra & 7)) << 4));
        }
        __syncthreads();                       // A-frag reads done; ldsA reusable
#pragma unroll 1
        for (int rp = 0; rp < 4; ++rp) {
            stage128(ldsA, Bc + (size_t)(2 * rp + 1) * I, KEXT);   // B[2rp+1]
            computeR(ldsB, 2 * rp);
            __syncthreads();                   // drains stage, reads done
            stage128(ldsB, Bc + (size_t)(2 * rp + 2) * I, KEXT);   // B[2rp+2]
            computeR(ldsA, 2 * rp + 1);
            __syncthreads();
        }
        computeR(ldsB, 8);
        __syncthreads();
    }

    // ---- bias K-step: A-cols = e (bf16), B-rows = b (k0 = RI), stride 128 B
    {
#pragma unroll
        for (int rr = 0; rr < 4; ++rr) {
            const int q    = rr * 256 + tid;
            const int row  = q >> 3;
            const int jsrc = (q & 7) ^ (row & 7);
            __builtin_amdgcn_global_load_lds(
                (const __attribute__((address_space(1))) void*)
                    (Bt + (size_t)(bn0 + row) * KEXT + RI + (jsrc << 3)),
                (__attribute__((address_space(3))) void*)(ldsB + q * 16), 16, 0, 0);
        }
#pragma unroll
        for (int rr = 0; rr < 4; ++rr) {
            const int q   = rr * 256 + tid;
            const int row = q >> 3;
            const int j   = q & 7;
            bf16x8 pv;
#pragma unroll
            for (int e8 = 0; e8 < 8; ++e8) {
                const int kl = j * 8 + e8;
                pv[e8] = (kl < 9) ? (__bf16)E[(size_t)(bm0 + row) * 9 + kl] : (__bf16)0.f;
            }
            *(bf16x8*)(ldsA + row * 128 + ((j ^ (row & 7)) << 4)) = pv;
        }
        __syncthreads();
#pragma unroll
        for (int ks = 0; ks < 2; ++ks) {
            bf16x8 av[4], bv[4];
#pragma unroll
            for (int m = 0; m < 4; ++m) {
                const int ra = wr + m * 16 + l15;
                av[m] = *(const bf16x8*)(ldsA + ra * 128 + ((((ks << 1) + (lq & 1) + ((lq >> 1) << 1) + (ks << 2) - (ks << 1) - ((lq >> 1) << 1) - (lq & 1) + ((ks << 2) + lq)) ^ (ra & 7)) << 4));
            }
#pragma unroll
            for (int n = 0; n < 4; ++n) {
                const int rb = wc + n * 16 + l15;
                bv[n] = *(const bf16x8*)(ldsB + rb * 128 + ((((ks << 2) + lq) ^ (rb & 7)) << 4));
            }
#pragma unroll
            for (int m = 0; m < 4; ++m)
#pragma unroll
                for (int n = 0; n < 4; ++n)
                    acc[m][n] = __builtin_amdgcn_mfma_f32_16x16x32_bf16(
                        av[m], bv[n], acc[m][n], 0, 0, 0);
        }
    }

    // epilogue: C/D layout col = lane&15, row = (lane>>4)*4 + reg
    const int orow0 = bm0 + wr + lq * 4;
    const int ocol0 = bn0 + wc + l15;
#pragma unroll
    for (int m = 0; m < 4; ++m) {
#pragma unroll
        for (int n = 0; n < 4; ++n) {
#pragma unroll
            for (int jj = 0; jj < 4; ++jj) {
                float v = acc[m][n][jj];
                if (RELU) v = fmaxf(v, 0.f);
                const size_t idx = (size_t)(orow0 + m * 16 + jj) * O + (ocol0 + n * 16);
                if (OUTF32) ((float*)Outv)[idx] = v;
                else        ((__bf16*)Outv)[idx] = (__bf16)v;
            }
        }
    }
}

// ---------------------------------------------------------------------------
extern "C" void kernel_launch(void* const* d_in, const int* in_sizes, int n_in,
                              void* d_out, int out_size, void* d_ws, size_t ws_size,
                              hipStream_t stream) {
    const float* x  = (const float*)d_in[0];
    const float* E  = (const float*)d_in[1];
    const float* W0 = (const float*)d_in[2];
    const float* b0 = (const float*)d_in[3];
    const float* W1 = (const float*)d_in[4];
    const float* b1 = (const float*)d_in[5];
    const float* W2 = (const float*)d_in[6];
    const float* b2 = (const float*)d_in[7];
    const float* W3 = (const float*)d_in[8];
    const float* b3 = (const float*)d_in[9];

    char* ws = (char*)d_ws;
    const size_t actBytes = (size_t)65536 * 512 * 2;           // 64 MiB each
    __bf16* actA = (__bf16*)ws;
    __bf16* actB = (__bf16*)(ws + actBytes);
    char* p = ws + 2 * actBytes;
    __bf16* Bt0 = (__bf16*)p; p += (size_t)512 * 2368 * 2;
    __bf16* Bt1 = (__bf16*)p; p += (size_t)512 * 4672 * 2;
    __bf16* Bt2 = (__bf16*)p; p += (size_t)512 * 4672 * 2;
    __bf16* Bt3 = (__bf16*)p; p += (size_t)256 * 4672 * 2;
    float*  Et  = (float*)p;  p += (size_t)9 * 65536 * 4;
    if (ws_size < (size_t)(p - ws)) return;   // ws too small -> visible failure

    // prep
    cvt_x_kernel<<<dim3(8192), dim3(256), 0, stream>>>(x, actA);
    prep_et_kernel<<<dim3(256), dim3(256), 0, stream>>>(E, Et);
    prep_w_kernel<256, 512><<<dim3(2, 512), dim3(256), 0, stream>>>(W0, b0, Bt0);
    prep_w_kernel<512, 512><<<dim3(3, 512), dim3(256), 0, stream>>>(W1, b1, Bt1);
    prep_w_kernel<512, 512><<<dim3(3, 512), dim3(256), 0, stream>>>(W2, b2, Bt2);
    prep_w_kernel<512, 256><<<dim3(3, 256), dim3(256), 0, stream>>>(W3, b3, Bt3);

    // 4 fused layers
    kg_gemm<256, 512, true,  false><<<dim3(512 * 4), dim3(256), 0, stream>>>(actA, E, Et, Bt0, actB);
    kg_gemm<512, 512, true,  false><<<dim3(512 * 4), dim3(256), 0, stream>>>(actB, E, Et, Bt1, actA);
    kg_gemm<512, 512, true,  false><<<dim3(512 * 4), dim3(256), 0, stream>>>(actA, E, Et, Bt2, actB);
    kg_gemm<512, 256, false, true ><<<dim3(512 * 2), dim3(256), 0, stream>>>(actB, E, Et, Bt3, d_out);
}

// Round 4
// 919.120 us; speedup vs baseline: 1.3244x; 1.3244x over previous
//
#include <hip/hip_runtime.h>
#include <stdint.h>

using f32x4  = __attribute__((ext_vector_type(4))) float;
using bf16x8 = __attribute__((ext_vector_type(8))) __bf16;

// ===========================================================================
// Fragment-major tile layout (the whole point of this round):
//   A 128x128 bf16 tile = 32 frags (f = mi*4 + ks; mi=row/16, ks=k/32).
//   Frag = 64 lanes x 16B; lane (l15,lq) holds T[row = mi*16+l15][k = ks*32+lq*8 .. +8].
//   Unit index u in tile = f*64 + lane; byte = u*16. Global stores tiles in
//   this unit order -> global_load_lds sources are LINEAR (perfect coalesce)
//   and every ds_read_b128 is base + f*1024 + lane*16 = DMA identity pattern
//   (conflict-free by construction).
// ===========================================================================

// x (fp32, row-major N x 256) -> actA frag-major bf16 (I=256, NCH=2)
__global__ void cvt_x_kernel(const float* __restrict__ x, __bf16* __restrict__ out) {
    const int u    = blockIdx.x * 256 + threadIdx.x;     // unit id, < 512*2*2048
    const int lane = u & 63;
    const int f    = (u >> 6) & 31;
    const int c    = (u >> 11) & 1;
    const int rb   = u >> 12;
    const int row  = rb * 128 + ((f >> 2) << 4) + (lane & 15);
    const int i    = c * 128 + ((f & 3) << 5) + ((lane >> 4) << 3);
    const float4 a = *(const float4*)(x + (size_t)row * 256 + i);
    const float4 b = *(const float4*)(x + (size_t)row * 256 + i + 4);
    bf16x8 pv;
    pv[0] = (__bf16)a.x; pv[1] = (__bf16)a.y; pv[2] = (__bf16)a.z; pv[3] = (__bf16)a.w;
    pv[4] = (__bf16)b.x; pv[5] = (__bf16)b.y; pv[6] = (__bf16)b.z; pv[7] = (__bf16)b.w;
    *(bf16x8*)(out + (size_t)u * 8) = pv;
}

// W (R x O x I fp32) -> Bt frag-major bf16: tile (nb, r, c) of B^T (row=out-col)
// grid: x = NCH*8 blocks, y = r (9), z = nb (O/128)
template<int I, int O>
__global__ void prep_w_kernel(const float* __restrict__ W, __bf16* __restrict__ Bt) {
    constexpr int NCH = I >> 7;
    const int u    = blockIdx.x * 256 + threadIdx.x;     // < NCH*2048
    const int r    = blockIdx.y;
    const int nb   = blockIdx.z;
    const int lane = u & 63;
    const int f    = (u >> 6) & 31;
    const int c    = u >> 11;
    const int row  = nb * 128 + ((f >> 2) << 4) + (lane & 15);
    const int i    = c * 128 + ((f & 3) << 5) + ((lane >> 4) << 3);
    const float* src = W + ((size_t)r * O + row) * I + i;
    const float4 a = *(const float4*)src;
    const float4 b = *(const float4*)(src + 4);
    bf16x8 pv;
    pv[0] = (__bf16)a.x; pv[1] = (__bf16)a.y; pv[2] = (__bf16)a.z; pv[3] = (__bf16)a.w;
    pv[4] = (__bf16)b.x; pv[5] = (__bf16)b.y; pv[6] = (__bf16)b.z; pv[7] = (__bf16)b.w;
    *(bf16x8*)(Bt + (((size_t)nb * 9 + r) * NCH * 2048 + u) * 8) = pv;
}

// bias tiles: per nb one 128x64 tile, 16 frags (f = ni*2 + ks2); B[col][k] = b[k][col] (k<9)
template<int O>
__global__ void prep_bias_kernel(const float* __restrict__ b, __bf16* __restrict__ BtB) {
    const int u    = blockIdx.x * 256 + threadIdx.x;     // < (O/128)*1024
    const int nb   = u >> 10;
    const int q    = u & 1023;
    const int lane = q & 63;
    const int f    = q >> 6;
    const int row  = nb * 128 + ((f >> 1) << 4) + (lane & 15);
    const int kb   = ((f & 1) << 5) + ((lane >> 4) << 3);
    bf16x8 pv;
#pragma unroll
    for (int e = 0; e < 8; ++e) {
        const int k = kb + e;
        pv[e] = (k < 9) ? (__bf16)b[(size_t)k * O + row] : (__bf16)0.f;
    }
    *(bf16x8*)(BtB + (size_t)u * 8) = pv;
}

// ---------------------------------------------------------------------------
// Relation-mixed GEMM (round-2 structure, frag-major addressing):
//   y[n,o] = sum_r e[n,r]*(sum_i x[n,i] W[r,o,i]) + sum_r e[n,r] b[r,o]
// Per 128-col i-chunk: stage A once; per r stage B, MFMA into acc2 (C-in=0),
// fold acc += e_r * acc2 (e fp32 from ldsE). Bias = one extra K=64 step.
// 128x128 tile, 4 waves, mfma_f32_16x16x32_bf16.
// ---------------------------------------------------------------------------
template<int I, int O, bool RELU, bool OUTF32>
__global__ __launch_bounds__(256, 2)
void kg_gemm(const __bf16* __restrict__ A, const float* __restrict__ E,
             const __bf16* __restrict__ Bt, const __bf16* __restrict__ BtB,
             void* __restrict__ Outv) {
    constexpr int NCH = I >> 7;
    constexpr int NBN = O >> 7;
    static_assert((I & 127) == 0 && (O & 127) == 0, "tile divisibility");

    __shared__ __align__(16) char lds[65536 + 4608];
    char*  const ldsA = lds;
    char*  const ldsB = lds + 32768;
    float* const ldsE = (float*)(lds + 65536);   // Et[r][row], r<9, row<128

    const int tid  = threadIdx.x;
    const int nwg  = gridDim.x;
    const int braw = blockIdx.x;
    const int bid  = (braw & 7) * (nwg >> 3) + (braw >> 3);   // XCD swizzle (nwg%8==0)
    const int rb   = bid / NBN;
    const int nb   = bid % NBN;
    const int bm0  = rb << 7;
    const int bn0  = nb << 7;
    const int lane = tid & 63;
    const int wid  = tid >> 6;
    const int wr   = (wid >> 1) << 6;
    const int wc   = (wid & 1) << 6;
    const int l15  = lane & 15;
    const int lq   = lane >> 4;

    if (tid < 128) {
        const float* e = E + (size_t)(bm0 + tid) * 9;
#pragma unroll
        for (int q = 0; q < 9; ++q) ldsE[q * 128 + tid] = e[q];
    }

    f32x4 acc[4][4];
#pragma unroll
    for (int m = 0; m < 4; ++m)
#pragma unroll
        for (int n = 0; n < 4; ++n)
            acc[m][n] = f32x4{0.f, 0.f, 0.f, 0.f};
    const f32x4 zero4 = {0.f, 0.f, 0.f, 0.f};

    const size_t Abase = (size_t)rb * NCH * 2048;       // units
    const size_t Bbase = (size_t)nb * 9 * NCH * 2048;   // units

    // stage one 32KB tile (2048 units), fully linear on both sides
    auto stageTile = [&](char* dst, const __bf16* srcElems) {
#pragma unroll
        for (int rr = 0; rr < 8; ++rr) {
            const int q = rr * 256 + tid;
            __builtin_amdgcn_global_load_lds(
                (const __attribute__((address_space(1))) void*)(srcElems + (size_t)q * 8),
                (__attribute__((address_space(3))) void*)(dst + q * 16), 16, 0, 0);
        }
    };

    const int afb = (wr >> 4) << 2;   // wave's A frag base (mi offset *4)
    const int bfb = (wc >> 4) << 2;   // wave's B frag base

#pragma unroll 1
    for (int c = 0; c < NCH; ++c) {
        stageTile(ldsA, A + (Abase + (size_t)c * 2048) * 8);
#pragma unroll 1
        for (int r = 0; r < 9; ++r) {
            stageTile(ldsB, Bt + (Bbase + ((size_t)r * NCH + c) * 2048) * 8);
            __syncthreads();
            f32x4 acc2[4][4];
#pragma unroll
            for (int ks = 0; ks < 4; ++ks) {
                bf16x8 av[4], bv[4];
#pragma unroll
                for (int m = 0; m < 4; ++m)
                    av[m] = *(const bf16x8*)(ldsA + (((afb + (m << 2) + ks) << 6) + lane) * 16);
#pragma unroll
                for (int n = 0; n < 4; ++n)
                    bv[n] = *(const bf16x8*)(ldsB + (((bfb + (n << 2) + ks) << 6) + lane) * 16);
#pragma unroll
                for (int m = 0; m < 4; ++m)
#pragma unroll
                    for (int n = 0; n < 4; ++n)
                        acc2[m][n] = __builtin_amdgcn_mfma_f32_16x16x32_bf16(
                            av[m], bv[n], (ks == 0) ? zero4 : acc2[m][n], 0, 0, 0);
            }
#pragma unroll
            for (int m = 0; m < 4; ++m) {
                const f32x4 ev = *(const f32x4*)(ldsE + r * 128 + wr + m * 16 + lq * 4);
#pragma unroll
                for (int n = 0; n < 4; ++n)
#pragma unroll
                    for (int j = 0; j < 4; ++j)
                        acc[m][n][j] += ev[j] * acc2[m][n][j];
            }
            __syncthreads();
        }
    }

    // ---- bias K=64 step: A-cols = e (built from ldsE), B = BtB tile
    {
#pragma unroll
        for (int rr = 0; rr < 4; ++rr) {
            const int q = rr * 256 + tid;
            __builtin_amdgcn_global_load_lds(
                (const __attribute__((address_space(1))) void*)
                    (BtB + ((size_t)nb * 1024 + q) * 8),
                (__attribute__((address_space(3))) void*)(ldsB + q * 16), 16, 0, 0);
        }
#pragma unroll
        for (int rr = 0; rr < 4; ++rr) {
            const int q    = rr * 256 + tid;
            const int ln   = q & 63;
            const int f    = q >> 6;                       // ni*2 + ks2
            const int row  = ((f >> 1) << 4) + (ln & 15);
            const int kb   = ((f & 1) << 5) + ((ln >> 4) << 3);
            bf16x8 pv;
#pragma unroll
            for (int e8 = 0; e8 < 8; ++e8) {
                const int k = kb + e8;
                pv[e8] = (k < 9) ? (__bf16)ldsE[k * 128 + row] : (__bf16)0.f;
            }
            *(bf16x8*)(ldsA + q * 16) = pv;
        }
        __syncthreads();
#pragma unroll
        for (int ks = 0; ks < 2; ++ks) {
            bf16x8 av[4], bv[4];
#pragma unroll
            for (int m = 0; m < 4; ++m)
                av[m] = *(const bf16x8*)(ldsA + (((((wr >> 4) + m) * 2 + ks) << 6) + lane) * 16);
#pragma unroll
            for (int n = 0; n < 4; ++n)
                bv[n] = *(const bf16x8*)(ldsB + (((((wc >> 4) + n) * 2 + ks) << 6) + lane) * 16);
#pragma unroll
            for (int m = 0; m < 4; ++m)
#pragma unroll
                for (int n = 0; n < 4; ++n)
                    acc[m][n] = __builtin_amdgcn_mfma_f32_16x16x32_bf16(
                        av[m], bv[n], acc[m][n], 0, 0, 0);
        }
    }

    // ---- epilogue: C/D layout col = l15, row = lq*4 + j
    if (OUTF32) {
        const int orow0 = bm0 + wr + lq * 4;
        const int ocol0 = bn0 + wc + l15;
#pragma unroll
        for (int m = 0; m < 4; ++m)
#pragma unroll
            for (int n = 0; n < 4; ++n)
#pragma unroll
                for (int j = 0; j < 4; ++j) {
                    float v = acc[m][n][j];
                    if (RELU) v = fmaxf(v, 0.f);
                    ((float*)Outv)[(size_t)(orow0 + m * 16 + j) * O + (ocol0 + n * 16)] = v;
                }
    } else {
        // write next layer's A in frag-major (I' = O)
        constexpr int NCHn = O >> 7;
        __bf16* outp = (__bf16*)Outv;
#pragma unroll
        for (int m = 0; m < 4; ++m) {
#pragma unroll
            for (int n = 0; n < 4; ++n) {
                const int col  = bn0 + wc + n * 16 + l15;
                const int c2   = col >> 7;
                const int f2   = (((wr >> 4) + m) << 2) + ((col >> 5) & 3);
                const int ln2  = ((col >> 3) & 3) * 16 + lq * 4;
                const size_t base =
                    (((size_t)rb * NCHn + c2) * 2048 + f2 * 64 + ln2) * 8 + (col & 7);
#pragma unroll
                for (int j = 0; j < 4; ++j) {
                    float v = acc[m][n][j];
                    if (RELU) v = fmaxf(v, 0.f);
                    outp[base + (size_t)j * 8] = (__bf16)v;
                }
            }
        }
    }
}

// ---------------------------------------------------------------------------
extern "C" void kernel_launch(void* const* d_in, const int* in_sizes, int n_in,
                              void* d_out, int out_size, void* d_ws, size_t ws_size,
                              hipStream_t stream) {
    const float* x  = (const float*)d_in[0];
    const float* E  = (const float*)d_in[1];
    const float* W0 = (const float*)d_in[2];
    const float* b0 = (const float*)d_in[3];
    const float* W1 = (const float*)d_in[4];
    const float* b1 = (const float*)d_in[5];
    const float* W2 = (const float*)d_in[6];
    const float* b2 = (const float*)d_in[7];
    const float* W3 = (const float*)d_in[8];
    const float* b3 = (const float*)d_in[9];

    char* ws = (char*)d_ws;
    const size_t actBytes = (size_t)65536 * 512 * 2;           // 64 MiB each
    __bf16* actA = (__bf16*)ws;
    __bf16* actB = (__bf16*)(ws + actBytes);
    char* p = ws + 2 * actBytes;
    // Bt unit counts: nb * 9 * NCH * 2048 units * 16B
    __bf16* Bt0 = (__bf16*)p; p += (size_t)4 * 9 * 2 * 2048 * 16;
    __bf16* Bt1 = (__bf16*)p; p += (size_t)4 * 9 * 4 * 2048 * 16;
    __bf16* Bt2 = (__bf16*)p; p += (size_t)4 * 9 * 4 * 2048 * 16;
    __bf16* Bt3 = (__bf16*)p; p += (size_t)2 * 9 * 4 * 2048 * 16;
    __bf16* BtB0 = (__bf16*)p; p += (size_t)4 * 1024 * 16;
    __bf16* BtB1 = (__bf16*)p; p += (size_t)4 * 1024 * 16;
    __bf16* BtB2 = (__bf16*)p; p += (size_t)4 * 1024 * 16;
    __bf16* BtB3 = (__bf16*)p; p += (size_t)2 * 1024 * 16;
    if (ws_size < (size_t)(p - ws)) return;   // ws too small -> visible failure

    // prep (all frag-major)
    cvt_x_kernel<<<dim3(8192), dim3(256), 0, stream>>>(x, actA);
    prep_w_kernel<256, 512><<<dim3(16, 9, 4), dim3(256), 0, stream>>>(W0, Bt0);
    prep_w_kernel<512, 512><<<dim3(32, 9, 4), dim3(256), 0, stream>>>(W1, Bt1);
    prep_w_kernel<512, 512><<<dim3(32, 9, 4), dim3(256), 0, stream>>>(W2, Bt2);
    prep_w_kernel<512, 256><<<dim3(32, 9, 2), dim3(256), 0, stream>>>(W3, Bt3);
    prep_bias_kernel<512><<<dim3(16), dim3(256), 0, stream>>>(b0, BtB0);
    prep_bias_kernel<512><<<dim3(16), dim3(256), 0, stream>>>(b1, BtB1);
    prep_bias_kernel<512><<<dim3(16), dim3(256), 0, stream>>>(b2, BtB2);
    prep_bias_kernel<256><<<dim3(8),  dim3(256), 0, stream>>>(b3, BtB3);

    // 4 fused layers
    kg_gemm<256, 512, true,  false><<<dim3(2048), dim3(256), 0, stream>>>(actA, E, Bt0, BtB0, actB);
    kg_gemm<512, 512, true,  false><<<dim3(2048), dim3(256), 0, stream>>>(actB, E, Bt1, BtB1, actA);
    kg_gemm<512, 512, true,  false><<<dim3(2048), dim3(256), 0, stream>>>(actA, E, Bt2, BtB2, actB);
    kg_gemm<512, 256, false, true ><<<dim3(1024), dim3(256), 0, stream>>>(actB, E, Bt3, BtB3, d_out);
}

// Round 5
// 837.881 us; speedup vs baseline: 1.4528x; 1.0970x over previous
//
#include <hip/hip_runtime.h>
#include <stdint.h>

using f32x4  = __attribute__((ext_vector_type(4))) float;
using bf16x8 = __attribute__((ext_vector_type(8))) __bf16;

#define GLOAD_LDS16(src, dst) __builtin_amdgcn_global_load_lds(                 \
    (const __attribute__((address_space(1))) void*)(src),                      \
    (__attribute__((address_space(3))) void*)(dst), 16, 0, 0)

// ===========================================================================
// Fragment-major tile layout (proven conflict-free in round 4):
//   A 128x128 bf16 tile = 32 frags f = mi*4 + ks (mi=row/16, ks=k/32).
//   Frag = 64 lanes x 16B; lane (l15,lq) holds T[mi*16+l15][ks*32+lq*8 ..+8].
//   A unit order: u = f*64 + lane (round-4 mapping, unchanged).
//   B tiles are stored HALF-CONTIGUOUS for the ring pipeline:
//     unit w = h*1024 + g*64 + lane, g = mi*2 + j, ks = 2h + j.
//   global_load_lds sources linear; ds_read_b128 = DMA identity pattern.
// ===========================================================================

// x (fp32, row-major N x 256) -> actA frag-major bf16 (I=256, NCH=2)
__global__ void cvt_x_kernel(const float* __restrict__ x, __bf16* __restrict__ out) {
    const int u    = blockIdx.x * 256 + threadIdx.x;
    const int lane = u & 63;
    const int f    = (u >> 6) & 31;
    const int c    = (u >> 11) & 1;
    const int rb   = u >> 12;
    const int row  = rb * 128 + ((f >> 2) << 4) + (lane & 15);
    const int i    = c * 128 + ((f & 3) << 5) + ((lane >> 4) << 3);
    const float4 a = *(const float4*)(x + (size_t)row * 256 + i);
    const float4 b = *(const float4*)(x + (size_t)row * 256 + i + 4);
    bf16x8 pv;
    pv[0] = (__bf16)a.x; pv[1] = (__bf16)a.y; pv[2] = (__bf16)a.z; pv[3] = (__bf16)a.w;
    pv[4] = (__bf16)b.x; pv[5] = (__bf16)b.y; pv[6] = (__bf16)b.z; pv[7] = (__bf16)b.w;
    *(bf16x8*)(out + (size_t)u * 8) = pv;
}

// W (R x O x I fp32) -> Bt frag-major bf16, half-contiguous unit order.
// grid: x = NCH*8 blocks, y = r (9), z = nb (O/128)
template<int I, int O>
__global__ void prep_w_kernel(const float* __restrict__ W, __bf16* __restrict__ Bt) {
    constexpr int NCH = I >> 7;
    const int u    = blockIdx.x * 256 + threadIdx.x;     // < NCH*2048
    const int r    = blockIdx.y;
    const int nb   = blockIdx.z;
    const int lane = u & 63;
    const int g    = (u >> 6) & 15;
    const int h    = (u >> 10) & 1;
    const int c    = u >> 11;
    const int mi   = g >> 1;
    const int ks   = (h << 1) + (g & 1);
    const int row  = nb * 128 + mi * 16 + (lane & 15);
    const int i    = c * 128 + ks * 32 + ((lane >> 4) << 3);
    const float* src = W + ((size_t)r * O + row) * I + i;
    const float4 a = *(const float4*)src;
    const float4 b = *(const float4*)(src + 4);
    bf16x8 pv;
    pv[0] = (__bf16)a.x; pv[1] = (__bf16)a.y; pv[2] = (__bf16)a.z; pv[3] = (__bf16)a.w;
    pv[4] = (__bf16)b.x; pv[5] = (__bf16)b.y; pv[6] = (__bf16)b.z; pv[7] = (__bf16)b.w;
    *(bf16x8*)(Bt + ((((size_t)nb * 9 + r) * NCH + c) * 2048 + (u & 2047)) * 8) = pv;
}

// bias tiles: per nb one 128x64 tile, 16 frags (f = ni*2 + ks2)
template<int O>
__global__ void prep_bias_kernel(const float* __restrict__ b, __bf16* __restrict__ BtB) {
    const int u    = blockIdx.x * 256 + threadIdx.x;     // < (O/128)*1024
    const int nb   = u >> 10;
    const int q    = u & 1023;
    const int lane = q & 63;
    const int f    = q >> 6;
    const int row  = nb * 128 + ((f >> 1) << 4) + (lane & 15);
    const int kb   = ((f & 1) << 5) + ((lane >> 4) << 3);
    bf16x8 pv;
#pragma unroll
    for (int e = 0; e < 8; ++e) {
        const int k = kb + e;
        pv[e] = (k < 9) ? (__bf16)b[(size_t)k * O + row] : (__bf16)0.f;
    }
    *(bf16x8*)(BtB + (size_t)u * 8) = pv;
}

// ---------------------------------------------------------------------------
// Relation-mixed GEMM with half-tile ring pipeline (T3+T4-style counted vmcnt):
//   y[n,o] = sum_r e[n,r]*(sum_i x[n,i] W[r,o,i]) + sum_r e[n,r] b[r,o]
// Per 128-col i-chunk: stage A once (stable across 9 r's); B streams through
// two 16KB half-buffers. Sub-phase (r,h): vmcnt(4) counted wait -> barrier ->
// read bv -> lgkm0 -> barrier -> issue stage B[r+1].h into same buffer ->
// read av (A stable) -> setprio(1) 32 MFMA setprio(0). Fold acc += e_r*acc2
// after h=1. Bias = one extra K=64 step. 128x128 tile, 4 waves.
// ---------------------------------------------------------------------------
template<int I, int O, bool RELU, bool OUTF32>
__global__ __launch_bounds__(256, 2)
void kg_gemm(const __bf16* __restrict__ A, const float* __restrict__ E,
             const __bf16* __restrict__ Bt, const __bf16* __restrict__ BtB,
             void* __restrict__ Outv) {
    constexpr int NCH = I >> 7;
    constexpr int NBN = O >> 7;
    static_assert((I & 127) == 0 && (O & 127) == 0, "tile divisibility");

    __shared__ __align__(16) char lds[32768 + 2 * 16384 + 4608];
    char*  const ldsA  = lds;
    char*  const ldsB0 = lds + 32768;
    char*  const ldsB1 = lds + 49152;
    float* const ldsE  = (float*)(lds + 65536);   // Et[r][row]

    const int tid  = threadIdx.x;
    const int nwg  = gridDim.x;
    const int braw = blockIdx.x;
    const int bid  = (braw & 7) * (nwg >> 3) + (braw >> 3);   // XCD swizzle (nwg%8==0)
    const int rb   = bid / NBN;
    const int nb   = bid % NBN;
    const int bm0  = rb << 7;
    const int bn0  = nb << 7;
    const int lane = tid & 63;
    const int wid  = tid >> 6;
    const int wr   = (wid >> 1) << 6;
    const int wc   = (wid & 1) << 6;
    const int l15  = lane & 15;
    const int lq   = lane >> 4;

    if (tid < 128) {
        const float* e = E + (size_t)(bm0 + tid) * 9;
#pragma unroll
        for (int q = 0; q < 9; ++q) ldsE[q * 128 + tid] = e[q];
    }

    f32x4 acc[4][4];
#pragma unroll
    for (int m = 0; m < 4; ++m)
#pragma unroll
        for (int n = 0; n < 4; ++n)
            acc[m][n] = f32x4{0.f, 0.f, 0.f, 0.f};
    const f32x4 zero4 = {0.f, 0.f, 0.f, 0.f};

    const size_t Abase = (size_t)rb * NCH * 2048;       // units
    const size_t Bbase = (size_t)nb * 9 * NCH * 2048;   // units
    const int afb = (wr >> 4) << 2;   // A frag base
    const int nfb = (wc >> 4) << 1;   // B g base

    auto stageA = [&](int c) {
        const __bf16* src = A + (Abase + (size_t)c * 2048) * 8;
#pragma unroll
        for (int rr = 0; rr < 8; ++rr) {
            const int q = rr * 256 + tid;
            GLOAD_LDS16(src + (size_t)q * 8, ldsA + q * 16);
        }
    };
    auto stageBh = [&](int r, int c, char* dst, int h) {
        const __bf16* src = Bt + (Bbase + ((size_t)r * NCH + c) * 2048 + (size_t)(h << 10)) * 8;
#pragma unroll
        for (int it = 0; it < 4; ++it) {
            const int q = it * 256 + tid;
            GLOAD_LDS16(src + (size_t)q * 8, dst + q * 16);
        }
    };

#pragma unroll 1
    for (int c = 0; c < NCH; ++c) {
        // chunk-top: all waves done reading ldsA / buffers from previous chunk
        asm volatile("s_waitcnt lgkmcnt(0)" ::: "memory");
        __builtin_amdgcn_s_barrier();
        __builtin_amdgcn_sched_barrier(0);
        stageA(c);                       // 8 loads
        stageBh(0, c, ldsB0, 0);         // 4 loads
        stageBh(0, c, ldsB1, 1);         // 4 loads
#pragma unroll 1
        for (int r = 0; r < 9; ++r) {
            f32x4 acc2[4][4];
#pragma unroll
            for (int h = 0; h < 2; ++h) {
                char* const buf = h ? ldsB1 : ldsB0;
                // counted wait: stage for THIS buffer (issued 2 sub-phases ago
                // or in prologue) complete; newest 4 may remain in flight.
                if (r == 8 && h == 1) asm volatile("s_waitcnt vmcnt(0)" ::: "memory");
                else                  asm volatile("s_waitcnt vmcnt(4)" ::: "memory");
                __builtin_amdgcn_s_barrier();
                __builtin_amdgcn_sched_barrier(0);
                bf16x8 bv[4][2];
#pragma unroll
                for (int n = 0; n < 4; ++n)
#pragma unroll
                    for (int j = 0; j < 2; ++j)
                        bv[n][j] = *(const bf16x8*)(buf + (((nfb + 2 * n + j) << 6) + lane) * 16);
                asm volatile("s_waitcnt lgkmcnt(0)" ::: "memory");
                __builtin_amdgcn_sched_barrier(0);
                __builtin_amdgcn_s_barrier();          // all waves done reading buf
                __builtin_amdgcn_sched_barrier(0);
                if (r < 8) stageBh(r + 1, c, buf, h);  // refill same buffer
                bf16x8 av[4][2];                        // A stable: safe post-barrier
#pragma unroll
                for (int m = 0; m < 4; ++m)
#pragma unroll
                    for (int j = 0; j < 2; ++j)
                        av[m][j] = *(const bf16x8*)(ldsA + (((afb + (m << 2) + 2 * h + j) << 6) + lane) * 16);
                __builtin_amdgcn_s_setprio(1);
#pragma unroll
                for (int j = 0; j < 2; ++j)
#pragma unroll
                    for (int m = 0; m < 4; ++m)
#pragma unroll
                        for (int n = 0; n < 4; ++n)
                            acc2[m][n] = __builtin_amdgcn_mfma_f32_16x16x32_bf16(
                                av[m][j], bv[n][j],
                                (h == 0 && j == 0) ? zero4 : acc2[m][n], 0, 0, 0);
                __builtin_amdgcn_s_setprio(0);
            }
            // fold: acc += e[row][r] * acc2
#pragma unroll
            for (int m = 0; m < 4; ++m) {
                const f32x4 ev = *(const f32x4*)(ldsE + r * 128 + wr + m * 16 + lq * 4);
#pragma unroll
                for (int n = 0; n < 4; ++n)
#pragma unroll
                    for (int j = 0; j < 4; ++j)
                        acc[m][n][j] += ev[j] * acc2[m][n][j];
            }
        }
    }

    // ---- bias K=64 step: A-cols = e (built from ldsE), B = BtB tile
    __syncthreads();   // full drain; guards ldsA/ldsB0 overwrite
    {
#pragma unroll
        for (int rr = 0; rr < 4; ++rr) {
            const int q = rr * 256 + tid;
            GLOAD_LDS16(BtB + ((size_t)nb * 1024 + q) * 8, ldsB0 + q * 16);
        }
#pragma unroll
        for (int rr = 0; rr < 4; ++rr) {
            const int q    = rr * 256 + tid;
            const int ln   = q & 63;
            const int f    = q >> 6;                       // ni*2 + ks2
            const int row  = ((f >> 1) << 4) + (ln & 15);
            const int kb   = ((f & 1) << 5) + ((ln >> 4) << 3);
            bf16x8 pv;
#pragma unroll
            for (int e8 = 0; e8 < 8; ++e8) {
                const int k = kb + e8;
                pv[e8] = (k < 9) ? (__bf16)ldsE[k * 128 + row] : (__bf16)0.f;
            }
            *(bf16x8*)(ldsA + q * 16) = pv;
        }
        __syncthreads();
#pragma unroll
        for (int ks = 0; ks < 2; ++ks) {
            bf16x8 av[4], bv[4];
#pragma unroll
            for (int m = 0; m < 4; ++m)
                av[m] = *(const bf16x8*)(ldsA + (((((wr >> 4) + m) * 2 + ks) << 6) + lane) * 16);
#pragma unroll
            for (int n = 0; n < 4; ++n)
                bv[n] = *(const bf16x8*)(ldsB0 + (((((wc >> 4) + n) * 2 + ks) << 6) + lane) * 16);
#pragma unroll
            for (int m = 0; m < 4; ++m)
#pragma unroll
                for (int n = 0; n < 4; ++n)
                    acc[m][n] = __builtin_amdgcn_mfma_f32_16x16x32_bf16(
                        av[m], bv[n], acc[m][n], 0, 0, 0);
        }
    }

    // ---- epilogue: C/D layout col = l15, row = lq*4 + j
    if (OUTF32) {
        const int orow0 = bm0 + wr + lq * 4;
        const int ocol0 = bn0 + wc + l15;
#pragma unroll
        for (int m = 0; m < 4; ++m)
#pragma unroll
            for (int n = 0; n < 4; ++n)
#pragma unroll
                for (int j = 0; j < 4; ++j) {
                    float v = acc[m][n][j];
                    if (RELU) v = fmaxf(v, 0.f);
                    ((float*)Outv)[(size_t)(orow0 + m * 16 + j) * O + (ocol0 + n * 16)] = v;
                }
    } else {
        // write next layer's A in frag-major (I' = O)
        constexpr int NCHn = O >> 7;
        __bf16* outp = (__bf16*)Outv;
#pragma unroll
        for (int m = 0; m < 4; ++m) {
#pragma unroll
            for (int n = 0; n < 4; ++n) {
                const int col  = bn0 + wc + n * 16 + l15;
                const int c2   = col >> 7;
                const int f2   = (((wr >> 4) + m) << 2) + ((col >> 5) & 3);
                const int ln2  = ((col >> 3) & 3) * 16 + lq * 4;
                const size_t base =
                    (((size_t)rb * NCHn + c2) * 2048 + f2 * 64 + ln2) * 8 + (col & 7);
#pragma unroll
                for (int j = 0; j < 4; ++j) {
                    float v = acc[m][n][j];
                    if (RELU) v = fmaxf(v, 0.f);
                    outp[base + (size_t)j * 8] = (__bf16)v;
                }
            }
        }
    }
}

// ---------------------------------------------------------------------------
extern "C" void kernel_launch(void* const* d_in, const int* in_sizes, int n_in,
                              void* d_out, int out_size, void* d_ws, size_t ws_size,
                              hipStream_t stream) {
    const float* x  = (const float*)d_in[0];
    const float* E  = (const float*)d_in[1];
    const float* W0 = (const float*)d_in[2];
    const float* b0 = (const float*)d_in[3];
    const float* W1 = (const float*)d_in[4];
    const float* b1 = (const float*)d_in[5];
    const float* W2 = (const float*)d_in[6];
    const float* b2 = (const float*)d_in[7];
    const float* W3 = (const float*)d_in[8];
    const float* b3 = (const float*)d_in[9];

    char* ws = (char*)d_ws;
    const size_t actBytes = (size_t)65536 * 512 * 2;           // 64 MiB each
    __bf16* actA = (__bf16*)ws;
    __bf16* actB = (__bf16*)(ws + actBytes);
    char* p = ws + 2 * actBytes;
    __bf16* Bt0 = (__bf16*)p; p += (size_t)4 * 9 * 2 * 2048 * 16;
    __bf16* Bt1 = (__bf16*)p; p += (size_t)4 * 9 * 4 * 2048 * 16;
    __bf16* Bt2 = (__bf16*)p; p += (size_t)4 * 9 * 4 * 2048 * 16;
    __bf16* Bt3 = (__bf16*)p; p += (size_t)2 * 9 * 4 * 2048 * 16;
    __bf16* BtB0 = (__bf16*)p; p += (size_t)4 * 1024 * 16;
    __bf16* BtB1 = (__bf16*)p; p += (size_t)4 * 1024 * 16;
    __bf16* BtB2 = (__bf16*)p; p += (size_t)4 * 1024 * 16;
    __bf16* BtB3 = (__bf16*)p; p += (size_t)2 * 1024 * 16;
    if (ws_size < (size_t)(p - ws)) return;   // ws too small -> visible failure

    // prep (all frag-major; Bt half-contiguous)
    cvt_x_kernel<<<dim3(8192), dim3(256), 0, stream>>>(x, actA);
    prep_w_kernel<256, 512><<<dim3(16, 9, 4), dim3(256), 0, stream>>>(W0, Bt0);
    prep_w_kernel<512, 512><<<dim3(32, 9, 4), dim3(256), 0, stream>>>(W1, Bt1);
    prep_w_kernel<512, 512><<<dim3(32, 9, 4), dim3(256), 0, stream>>>(W2, Bt2);
    prep_w_kernel<512, 256><<<dim3(32, 9, 2), dim3(256), 0, stream>>>(W3, Bt3);
    prep_bias_kernel<512><<<dim3(16), dim3(256), 0, stream>>>(b0, BtB0);
    prep_bias_kernel<512><<<dim3(16), dim3(256), 0, stream>>>(b1, BtB1);
    prep_bias_kernel<512><<<dim3(16), dim3(256), 0, stream>>>(b2, BtB2);
    prep_bias_kernel<256><<<dim3(8),  dim3(256), 0, stream>>>(b3, BtB3);

    // 4 fused layers
    kg_gemm<256, 512, true,  false><<<dim3(2048), dim3(256), 0, stream>>>(actA, E, Bt0, BtB0, actB);
    kg_gemm<512, 512, true,  false><<<dim3(2048), dim3(256), 0, stream>>>(actB, E, Bt1, BtB1, actA);
    kg_gemm<512, 512, true,  false><<<dim3(2048), dim3(256), 0, stream>>>(actA, E, Bt2, BtB2, actB);
    kg_gemm<512, 256, false, true ><<<dim3(1024), dim3(256), 0, stream>>>(actB, E, Bt3, BtB3, d_out);
}